// Round 1
// 541.192 us; speedup vs baseline: 1.1100x; 1.1100x over previous
//
#include <hip/hip_runtime.h>
#include <hip/hip_bf16.h>

#define B_   128
#define S_   512
#define H_   128
#define G_   512   // 4*H
#define EMB_ 128
#define NL_  9
#define CPW_ 2     // chains per workgroup

typedef __attribute__((ext_vector_type(8))) short bf16x8;
typedef __attribute__((ext_vector_type(4))) float f32x4;
typedef unsigned short ushort_t;

// padded fragment slot: chunk stride 17
#define FRAG(c, r) ((c) * 17 + (r))

// LDS-only barrier: vmem ops stay in flight across it.
__device__ __forceinline__ void wg_bar() {
    asm volatile("s_waitcnt lgkmcnt(0)\n\ts_barrier" ::: "memory");
}

__device__ __forceinline__ float bfbits2f(short s) {
    unsigned int u = ((unsigned int)(unsigned short)s) << 16;
    return __builtin_bit_cast(float, u);
}
__device__ __forceinline__ short f2bf(float f) {
    unsigned int u = __builtin_bit_cast(unsigned int, f);
    u += 0x7FFFu + ((u >> 16) & 1u);
    return (short)(u >> 16);
}
__device__ __forceinline__ unsigned int pack2(float lo, float hi) {
    return (unsigned int)(unsigned short)f2bf(lo) | ((unsigned int)(unsigned short)f2bf(hi) << 16);
}
__device__ __forceinline__ float sigm(float x) {
    return __builtin_amdgcn_rcpf(1.f + exp2f(-1.4426950408889634f * x));
}
__device__ __forceinline__ float tanh_(float x) {
    return 1.f - 2.f * __builtin_amdgcn_rcpf(1.f + exp2f(2.8853900817779268f * x));
}

// ---------------------------------------------------------------------------
// xw pre-pass. Layout (ushorts):
//   xw[((((dir*64+pair)*512 + t)*8 + wv)*16 + n16)*8 + chain*4 + nt]
// Gate columns are INTERLEAVED: (wv,n16,nt) <-> gate col nt*128 + wv*16 + n16,
// i.e. nt indexes the gate type {i,f,g,o} for hidden unit wv*16+n16. This
// matches the recurrent kernel's in-register gate nonlinearity.
// ---------------------------------------------------------------------------
__global__ __launch_bounds__(512, 1)
void xw_gemm_kernel(const int* __restrict__ seq, const float* __restrict__ emb,
                    const float* __restrict__ w_ih_f, const float* __restrict__ b_ih_f,
                    const float* __restrict__ b_hh_f,
                    const float* __restrict__ w_ih_b, const float* __restrict__ b_ih_b,
                    const float* __restrict__ b_hh_b,
                    ushort_t* __restrict__ xw)
{
    __shared__ bf16x8 ldsX[64 * 17];

    const int tid  = threadIdx.x;
    const int wv   = tid >> 6;
    const int n16  = tid & 15;
    const int quad = (tid & 63) >> 4;
    const int dir  = blockIdx.x >> 10;
    const int rem  = blockIdx.x & 1023;
    const int pair = rem >> 4;
    const int tb   = (rem & 15) * 32;

    const float* wih = dir ? w_ih_b : w_ih_f;
    const float* bih = dir ? b_ih_b : b_ih_f;
    const float* bhh = dir ? b_hh_b : b_hh_f;

    // stage 64 rows: rows 0..31 chain0 (b=2*pair) t=tb..tb+31, rows 32..63 chain1
    {
        int row = tid >> 3, part = tid & 7;
        int b = 2 * pair + (row >> 5);
        int t = tb + (row & 31);
        int tok = seq[b * S_ + t];
        const float* ep = emb + (size_t)tok * EMB_ + part * 16;
        int rt = row >> 4, rr = row & 15;
#pragma unroll
        for (int h = 0; h < 2; h++) {
            float4 a = *(const float4*)(ep + h * 8);
            float4 b4 = *(const float4*)(ep + h * 8 + 4);
            bf16x8 fr;
            fr[0] = f2bf(a.x); fr[1] = f2bf(a.y); fr[2] = f2bf(a.z); fr[3] = f2bf(a.w);
            fr[4] = f2bf(b4.x); fr[5] = f2bf(b4.y); fr[6] = f2bf(b4.z); fr[7] = f2bf(b4.w);
            ldsX[(rt * 16 + part * 2 + h) * 17 + rr] = fr;
        }
    }

    bf16x8 bfrag[4][4];
    float  bias[4];
#pragma unroll
    for (int nt = 0; nt < 4; nt++) {
        int col = nt * 128 + wv * 16 + n16;   // gate-interleaved column mapping
        bias[nt] = bih[col] + bhh[col];
#pragma unroll
        for (int ks = 0; ks < 4; ks++) {
            const float* p = wih + col * EMB_ + ks * 32 + quad * 8;
            bf16x8 fr;
#pragma unroll
            for (int j = 0; j < 8; j++) fr[j] = f2bf(p[j]);
            bfrag[nt][ks] = fr;
        }
    }
    __syncthreads();

#pragma unroll
    for (int half = 0; half < 2; half++) {
        // chain0 tile = half, chain1 tile = half+2
        f32x4 accA[4], accB[4];
        bf16x8 afA[4], afB[4];
#pragma unroll
        for (int ks = 0; ks < 4; ks++) {
            afA[ks] = ldsX[(half * 16 + ks * 4 + quad) * 17 + n16];
            afB[ks] = ldsX[((half + 2) * 16 + ks * 4 + quad) * 17 + n16];
        }
#pragma unroll
        for (int nt = 0; nt < 4; nt++) {
            f32x4 a = {bias[nt], bias[nt], bias[nt], bias[nt]};
            accA[nt] = a; accB[nt] = a;
#pragma unroll
            for (int ks = 0; ks < 4; ks++) {
                accA[nt] = __builtin_amdgcn_mfma_f32_16x16x32_bf16(afA[ks], bfrag[nt][ks], accA[nt], 0, 0, 0);
                accB[nt] = __builtin_amdgcn_mfma_f32_16x16x32_bf16(afB[ks], bfrag[nt][ks], accB[nt], 0, 0, 0);
            }
        }
#pragma unroll
        for (int r = 0; r < 4; r++) {
            int t = tb + half * 16 + quad * 4 + r;
            int4 iv;
            iv.x = (int)pack2(accA[0][r], accA[1][r]);
            iv.y = (int)pack2(accA[2][r], accA[3][r]);
            iv.z = (int)pack2(accB[0][r], accB[1][r]);
            iv.w = (int)pack2(accB[2][r], accB[3][r]);
            size_t idx = ((((size_t)dir * 64 + pair) * S_ + t) * 8 + wv) * 16 + n16;
            *(int4*)(xw + idx * 8) = iv;
        }
    }
}

// ---------------------------------------------------------------------------
// Recurrent LSTM, single barrier per step:
//   - A-frag chain parity = (n16>>2)&1  =>  acc reg0 at quad q is chain q&1.
//   - Gate columns interleaved so each lane (quad<2) owns one (unit,chain)
//     item's full {i,f,g,o} in registers -> in-register c/h update, single
//     bf16 ds_write of h. No gates LDS exchange, no second barrier.
//   - h buffer double-buffered (parity = K&1, compile-time per step) so the
//     write to buf[p^1] cannot race other waves' reads of buf[p].
// ---------------------------------------------------------------------------
#define STEP(K)                                                                    \
  {                                                                                \
    const int u = m16 + (K);                                                       \
    if ((K) == 0 && m < 31) {                                                      \
      const ushort_t* gp = xwp + (size_t)(dir ? (S_ - 32 - m16) : (m16 + 16)) * 1024; \
      sA = *(const int4*)(gp + tid * 8);                                           \
      sB = *(const int4*)(gp + 4096 + tid * 8);                                    \
      sC = *(const int4*)(gp + 8192 + tid * 8);                                    \
      sD = *(const int4*)(gp + 12288 + tid * 8);                                   \
    }                                                                              \
    if ((K) == 8 && m < 31) {                                                      \
      int4* dst = (int4*)(xwL + (((m & 1) ^ 1) * 2048));                           \
      dst[tid] = sA; dst[512 + tid] = sB; dst[1024 + tid] = sC; dst[1536 + tid] = sD; \
    }                                                                              \
    if ((K) == 1 && m >= 1 && (wv == 4 || wv == 5) && lane < 36) {                 \
      int a0 = dir ? (S_ - m16) : (m16 - 16);                                      \
      int chain = wv - 4;                                                          \
      float4 fv;                                                                   \
      _Pragma("unroll")                                                            \
      for (int i = 0; i < 4; i++) {                                                \
        int q = lane * 4 + i;                                                      \
        int tq = a0 + q / 9, lq = q % 9;                                           \
        ((float*)&fv)[i] = emL[((tq & 31) * 9 + lq) * 2 + chain];                  \
      }                                                                            \
      *(float4*)(emdir + (size_t)(brow0 + chain) * (S_ * NL_) + a0 * NL_ + lane * 4) = fv; \
    }                                                                              \
    bf16x8 af0 = ldsH[(K) & 1][FRAG(0 + quad, hpar)];                              \
    bf16x8 af1 = ldsH[(K) & 1][FRAG(4 + quad, hpar)];                              \
    bf16x8 af2 = ldsH[(K) & 1][FRAG(8 + quad, hpar)];                              \
    bf16x8 af3 = ldsH[(K) & 1][FRAG(12 + quad, hpar)];                             \
    bf16x8 xv = xwL[(m & 1) * 2048 + ((dir ? (15 - (K)) : (K)) * 8 + wv) * 16 + n16]; \
    f32x4 acc0 = {bfbits2f(qodd ? xv[4] : xv[0]), 0.f, 0.f, 0.f};                  \
    f32x4 acc1 = {bfbits2f(qodd ? xv[5] : xv[1]), 0.f, 0.f, 0.f};                  \
    f32x4 acc2 = {bfbits2f(qodd ? xv[6] : xv[2]), 0.f, 0.f, 0.f};                  \
    f32x4 acc3 = {bfbits2f(qodd ? xv[7] : xv[3]), 0.f, 0.f, 0.f};                  \
    acc0 = __builtin_amdgcn_mfma_f32_16x16x32_bf16(af0, bfrag[0][0], acc0, 0, 0, 0); \
    acc1 = __builtin_amdgcn_mfma_f32_16x16x32_bf16(af0, bfrag[1][0], acc1, 0, 0, 0); \
    acc2 = __builtin_amdgcn_mfma_f32_16x16x32_bf16(af0, bfrag[2][0], acc2, 0, 0, 0); \
    acc3 = __builtin_amdgcn_mfma_f32_16x16x32_bf16(af0, bfrag[3][0], acc3, 0, 0, 0); \
    acc0 = __builtin_amdgcn_mfma_f32_16x16x32_bf16(af1, bfrag[0][1], acc0, 0, 0, 0); \
    acc1 = __builtin_amdgcn_mfma_f32_16x16x32_bf16(af1, bfrag[1][1], acc1, 0, 0, 0); \
    acc2 = __builtin_amdgcn_mfma_f32_16x16x32_bf16(af1, bfrag[2][1], acc2, 0, 0, 0); \
    acc3 = __builtin_amdgcn_mfma_f32_16x16x32_bf16(af1, bfrag[3][1], acc3, 0, 0, 0); \
    acc0 = __builtin_amdgcn_mfma_f32_16x16x32_bf16(af2, bfrag[0][2], acc0, 0, 0, 0); \
    acc1 = __builtin_amdgcn_mfma_f32_16x16x32_bf16(af2, bfrag[1][2], acc1, 0, 0, 0); \
    acc2 = __builtin_amdgcn_mfma_f32_16x16x32_bf16(af2, bfrag[2][2], acc2, 0, 0, 0); \
    acc3 = __builtin_amdgcn_mfma_f32_16x16x32_bf16(af2, bfrag[3][2], acc3, 0, 0, 0); \
    acc0 = __builtin_amdgcn_mfma_f32_16x16x32_bf16(af3, bfrag[0][3], acc0, 0, 0, 0); \
    acc1 = __builtin_amdgcn_mfma_f32_16x16x32_bf16(af3, bfrag[1][3], acc1, 0, 0, 0); \
    acc2 = __builtin_amdgcn_mfma_f32_16x16x32_bf16(af3, bfrag[2][3], acc2, 0, 0, 0); \
    acc3 = __builtin_amdgcn_mfma_f32_16x16x32_bf16(af3, bfrag[3][3], acc3, 0, 0, 0); \
    if (wv == 0) {                                                                 \
      f32x4 accE = {0.f, 0.f, 0.f, 0.f};                                           \
      accE = __builtin_amdgcn_mfma_f32_16x16x32_bf16(af0, bfragE[0], accE, 0, 0, 0); \
      accE = __builtin_amdgcn_mfma_f32_16x16x32_bf16(af1, bfragE[1], accE, 0, 0, 0); \
      accE = __builtin_amdgcn_mfma_f32_16x16x32_bf16(af2, bfragE[2], accE, 0, 0, 0); \
      accE = __builtin_amdgcn_mfma_f32_16x16x32_bf16(af3, bfragE[3], accE, 0, 0, 0); \
      if (quad < 2 && n16 < NL_ && u >= 1) {                                       \
        int tprev = dir ? (S_ - u) : (u - 1);                                      \
        emL[((tprev & 31) * 9 + n16) * 2 + quad] = accE[0];                        \
      }                                                                            \
    }                                                                              \
    if (quad < 2) {                                                                \
      cst = sigm(acc1[0]) * cst + sigm(acc0[0]) * tanh_(acc2[0]);                  \
      float hv = sigm(acc3[0]) * tanh_(cst);                                       \
      ((short*)&ldsH[((K) & 1) ^ 1][FRAG(hc, quad)])[hp] = f2bf(hv);               \
    }                                                                              \
    wg_bar();                                                                      \
  }

__global__ __launch_bounds__(512, 1)
void lstm_kernel(const ushort_t* __restrict__ xw,
                 const float* __restrict__ w_hh_f, const float* __restrict__ w_hh_b,
                 const float* __restrict__ w_out,
                 float* __restrict__ em_f, float* __restrict__ em_b)
{
    __shared__ bf16x8 xwL[2 * 2048];        // 64 KB: [buf][(slot*8+wv)*16+n16]
    __shared__ bf16x8 ldsH[2][16 * 17];     // 8704 B, double-buffered h
    __shared__ float  emL[32 * NL_ * 2];    // 2304 B: [slot][label][chain]

    const int tid  = threadIdx.x;
    const int wv   = tid >> 6;
    const int lane = tid & 63;
    const int n16  = tid & 15;
    const int quad = (tid & 63) >> 4;
    const int dir  = blockIdx.x >> 6;
    const int pair = blockIdx.x & 63;
    const int brow0 = pair * CPW_;

    const int hpar = (n16 >> 2) & 1;        // A-row chain parity
    const bool qodd = (quad & 1) != 0;      // acc reg0 chain at this quad
    const int hc = 2 * wv + (n16 >> 3);     // h chunk owned by this lane
    const int hp = n16 & 7;                 // position within chunk

    const float* whh = dir ? w_hh_b : w_hh_f;
    float* emdir = dir ? em_b : em_f;

    // B fragments: wave wv owns gate types nt for hidden units [wv*16, wv*16+16)
    bf16x8 bfrag[4][4];
#pragma unroll
    for (int nt = 0; nt < 4; nt++) {
        int col = nt * 128 + wv * 16 + n16;   // gate-interleaved column mapping
#pragma unroll
        for (int ks = 0; ks < 4; ks++) {
            const float* p = whh + col * H_ + ks * 32 + quad * 8;
            bf16x8 fr;
#pragma unroll
            for (int j = 0; j < 8; j++) fr[j] = f2bf(p[j]);
            bfrag[nt][ks] = fr;
        }
    }
    bf16x8 bfragE[4];
#pragma unroll
    for (int ks = 0; ks < 4; ks++) {
        bf16x8 fr = {0, 0, 0, 0, 0, 0, 0, 0};
        if (n16 < NL_) {
            const float* p = w_out + n16 * 256 + dir * 128 + ks * 32 + quad * 8;
#pragma unroll
            for (int j = 0; j < 8; j++) fr[j] = f2bf(p[j]);
        }
        bfragE[ks] = fr;
    }

    if (tid < 16 * 17) { bf16x8 z = {0,0,0,0,0,0,0,0}; ldsH[0][tid] = z; }

    const ushort_t* xwp = xw + (size_t)(dir * 64 + pair) * ((size_t)S_ * 1024);
    // pre-stage block 0
    {
        const ushort_t* gp = xwp + (size_t)(dir ? (S_ - 16) : 0) * 1024;
        int4 a0 = *(const int4*)(gp + tid * 8);
        int4 a1 = *(const int4*)(gp + 4096 + tid * 8);
        int4 a2 = *(const int4*)(gp + 8192 + tid * 8);
        int4 a3 = *(const int4*)(gp + 12288 + tid * 8);
        int4* dst = (int4*)xwL;
        dst[tid] = a0; dst[512 + tid] = a1; dst[1024 + tid] = a2; dst[1536 + tid] = a3;
    }

    float cst = 0.f;                        // c-state: lane (quad<2) owns (unit, chain=quad)
    int4 sA, sB, sC, sD;
    wg_bar();

    for (int m = 0; m < 32; m++) {
        const int m16 = m << 4;
        STEP(0)  STEP(1)  STEP(2)  STEP(3)
        STEP(4)  STEP(5)  STEP(6)  STEP(7)
        STEP(8)  STEP(9)  STEP(10) STEP(11)
        STEP(12) STEP(13) STEP(14) STEP(15)
    }

    // final emission (h_{S-1}) -> emL, then tail flush. 512 steps even ->
    // final h is in buffer 0.
    if (wv == 0) {
        bf16x8 af0 = ldsH[0][FRAG(0 + quad, hpar)];
        bf16x8 af1 = ldsH[0][FRAG(4 + quad, hpar)];
        bf16x8 af2 = ldsH[0][FRAG(8 + quad, hpar)];
        bf16x8 af3 = ldsH[0][FRAG(12 + quad, hpar)];
        f32x4 accE = {0.f, 0.f, 0.f, 0.f};
        accE = __builtin_amdgcn_mfma_f32_16x16x32_bf16(af0, bfragE[0], accE, 0, 0, 0);
        accE = __builtin_amdgcn_mfma_f32_16x16x32_bf16(af1, bfragE[1], accE, 0, 0, 0);
        accE = __builtin_amdgcn_mfma_f32_16x16x32_bf16(af2, bfragE[2], accE, 0, 0, 0);
        accE = __builtin_amdgcn_mfma_f32_16x16x32_bf16(af3, bfragE[3], accE, 0, 0, 0);
        if (quad < 2 && n16 < NL_) {
            int tprev = dir ? 0 : (S_ - 1);
            emL[((tprev & 31) * 9 + n16) * 2 + quad] = accE[0];
        }
    }
    wg_bar();
    if ((wv == 4 || wv == 5) && lane < 36) {
        int a0 = dir ? 0 : (S_ - 16);
        int chain = wv - 4;
        float4 fv;
#pragma unroll
        for (int i = 0; i < 4; i++) {
            int q = lane * 4 + i;
            int tq = a0 + q / 9, lq = q % 9;
            ((float*)&fv)[i] = emL[((tq & 31) * 9 + lq) * 2 + chain];
        }
        *(float4*)(emdir + (size_t)(brow0 + chain) * (S_ * NL_) + a0 * NL_ + lane * 4) = fv;
    }
}

// ---------------------------------------------------------------------------
// CRF with chunked parallel scan (unchanged — verified correct).
// ---------------------------------------------------------------------------
__global__ __launch_bounds__(640, 1)
void crf_kernel(const int* __restrict__ seq, const int* __restrict__ lab,
                const float* __restrict__ em_f, const float* __restrict__ em_b,
                const float* __restrict__ b_out,
                const float* __restrict__ start_t, const float* __restrict__ end_t,
                const float* __restrict__ trans, float* __restrict__ partial)
{
    __shared__ float emS[S_ * NL_];
    __shared__ float transS[NL_ * NL_];
    __shared__ float stS[NL_], enS[NL_];
    __shared__ unsigned char maskS[S_];
    __shared__ float MS[7 * 81];
    __shared__ float vS[NL_];
    __shared__ float redw[10];
    __shared__ int   redl[10];

    const int b = blockIdx.x, tid = threadIdx.x;
    const size_t base = (size_t)b * S_ * NL_;
    const float L2E = 1.4426950408889634f, LN2 = 0.6931471805599453f;

    for (int q = tid; q < S_ * NL_; q += 640)
        emS[q] = em_f[base + q] + em_b[base + q] + b_out[q % NL_];
    if (tid < NL_ * NL_) transS[tid] = trans[tid];
    if (tid < NL_) { stS[tid] = start_t[tid]; enS[tid] = end_t[tid]; }
    if (tid < S_) maskS[tid] = (seq[b * S_ + tid] != 0);
    __syncthreads();

    float np = 0.f; int myc = 0;
    if (tid < S_) {
        myc = maskS[tid];
        if (tid >= 1 && maskS[tid]) {
            int lp = lab[b * S_ + tid - 1], lc = lab[b * S_ + tid];
            np = transS[lp * NL_ + lc] + emS[tid * NL_ + lc];
        }
    }
#pragma unroll
    for (int off = 32; off; off >>= 1) {
        np  += __shfl_down(np, off, 64);
        myc += __shfl_down(myc, off, 64);
    }
    if ((tid & 63) == 0) { redw[tid >> 6] = np; redl[tid >> 6] = myc; }

    const int w = tid >> 6, l = tid & 63;
    const int lg = l / 9;
    const int g  = w * 7 + lg;
    const bool sact = (lg < 7) && (g < 64);
    const int jj = sact ? (l - lg * 9) : 0;
    const int gb = sact ? lg * 9 : 0;
    float Tc[NL_];
#pragma unroll
    for (int i = 0; i < NL_; i++) Tc[i] = transS[i * NL_ + jj];
    float sc; int tbeg, tend, cN = 0, iN = 0;
    if (sact && g == 0) {
        sc = stS[jj] + emS[jj];
        tbeg = 1; tend = 64;
    } else if (sact) {
        cN = 1 + (g - 1) / 9; iN = (g - 1) % 9;
        sc = (jj == iN) ? 0.f : -1e30f;
        tbeg = cN * 64; tend = tbeg + 64;
    } else {
        sc = -1e30f; tbeg = 448; tend = 512;
    }
    for (int t = tbeg; t < tend; t++) {
        float emv = emS[t * NL_ + jj];
        float a[NL_];
#pragma unroll
        for (int i = 0; i < NL_; i++) a[i] = __shfl(sc, gb + i, 64) + Tc[i];
        float m = a[0];
#pragma unroll
        for (int i = 1; i < NL_; i++) m = fmaxf(m, a[i]);
        float sum = 0.f;
#pragma unroll
        for (int i = 0; i < NL_; i++) sum += exp2f((a[i] - m) * L2E);
        float nxt = emv + m + LN2 * log2f(sum);
        sc = maskS[t] ? nxt : sc;
    }
    if (sact) {
        if (g == 0) vS[jj] = sc;
        else MS[(cN - 1) * 81 + iN * NL_ + jj] = sc;
    }
    __syncthreads();

    if (tid < 64) {
        const int j = (tid < NL_) ? tid : (NL_ - 1);
        float v = vS[j];
        for (int c = 1; c < 8; c++) {
            float a[NL_];
#pragma unroll
            for (int i = 0; i < NL_; i++)
                a[i] = __shfl(v, i, 64) + MS[(c - 1) * 81 + i * NL_ + j];
            float m = a[0];
#pragma unroll
            for (int i = 1; i < NL_; i++) m = fmaxf(m, a[i]);
            float sum = 0.f;
#pragma unroll
            for (int i = 0; i < NL_; i++) sum += exp2f((a[i] - m) * L2E);
            v = m + LN2 * log2f(sum);
        }
        v += enS[j];
        float mm = -1e30f, av[NL_];
#pragma unroll
        for (int i = 0; i < NL_; i++) { float vi = __shfl(v, i, 64); av[i] = vi; mm = fmaxf(mm, vi); }
        float ss = 0.f;
#pragma unroll
        for (int i = 0; i < NL_; i++) ss += exp2f((av[i] - mm) * L2E);
        if (tid == 0) {
            float num = 0.f; int len = 0;
#pragma unroll
            for (int ww = 0; ww < 10; ww++) { num += redw[ww]; len += redl[ww]; }
            int l0 = lab[b * S_];
            int ll = lab[b * S_ + len - 1];
            num += stS[l0] + emS[l0] + enS[ll];
            partial[b] = (mm + LN2 * log2f(ss)) - num;
        }
    }
}

__global__ __launch_bounds__(128)
void reduce_kernel(const float* __restrict__ partial, float* __restrict__ out)
{
    __shared__ float s[128];
    int tid = threadIdx.x;
    s[tid] = partial[tid];
    __syncthreads();
    for (int off = 64; off; off >>= 1) {
        if (tid < off) s[tid] += s[tid + off];
        __syncthreads();
    }
    if (tid == 0) out[0] = s[0];
}

extern "C" void kernel_launch(void* const* d_in, const int* in_sizes, int n_in,
                              void* d_out, int out_size, void* d_ws, size_t ws_size,
                              hipStream_t stream)
{
    const int* seq = (const int*)d_in[0];
    const int* lab = (const int*)d_in[1];
    const float* emb    = (const float*)d_in[2];
    const float* w_ih_f = (const float*)d_in[3];
    const float* w_hh_f = (const float*)d_in[4];
    const float* b_ih_f = (const float*)d_in[5];
    const float* b_hh_f = (const float*)d_in[6];
    const float* w_ih_b = (const float*)d_in[7];
    const float* w_hh_b = (const float*)d_in[8];
    const float* b_ih_b = (const float*)d_in[9];
    const float* b_hh_b = (const float*)d_in[10];
    const float* w_out  = (const float*)d_in[11];
    const float* b_out  = (const float*)d_in[12];
    const float* start_t = (const float*)d_in[13];
    const float* end_t   = (const float*)d_in[14];
    const float* trans   = (const float*)d_in[15];

    char* ws = (char*)d_ws;
    const size_t xw_bytes = (size_t)2 * B_ * S_ * G_ * sizeof(ushort_t);  // 134.2 MB
    const size_t em_bytes = (size_t)B_ * S_ * NL_ * sizeof(float);
    ushort_t* xw   = (ushort_t*)ws;
    float* em_f    = (float*)(ws + xw_bytes);
    float* em_b    = (float*)(ws + xw_bytes + em_bytes);
    float* partial = (float*)(ws + xw_bytes + 2 * em_bytes);

    xw_gemm_kernel<<<dim3(2048), dim3(512), 0, stream>>>(seq, emb,
        w_ih_f, b_ih_f, b_hh_f, w_ih_b, b_ih_b, b_hh_b, xw);
    lstm_kernel<<<dim3(128), dim3(512), 0, stream>>>(xw, w_hh_f, w_hh_b,
        w_out, em_f, em_b);
    crf_kernel<<<dim3(B_), dim3(640), 0, stream>>>(seq, lab, em_f, em_b, b_out,
        start_t, end_t, trans, partial);
    reduce_kernel<<<dim3(1), dim3(128), 0, stream>>>(partial, (float*)d_out);
}

// Round 2
// 521.736 us; speedup vs baseline: 1.1514x; 1.0373x over previous
//
#include <hip/hip_runtime.h>
#include <hip/hip_bf16.h>

#define B_   128
#define S_   512
#define H_   128
#define G_   512   // 4*H
#define EMB_ 128
#define NL_  9
#define CPW_ 2     // chains per workgroup

typedef __attribute__((ext_vector_type(8))) short bf16x8;
typedef __attribute__((ext_vector_type(4))) short bf16x4;
typedef __attribute__((ext_vector_type(4))) float f32x4;
typedef unsigned short ushort_t;

// LDS-only barrier: vmem ops stay in flight across it.
__device__ __forceinline__ void wg_bar() {
    asm volatile("s_waitcnt lgkmcnt(0)\n\ts_barrier" ::: "memory");
}

__device__ __forceinline__ float bfbits2f(short s) {
    unsigned int u = ((unsigned int)(unsigned short)s) << 16;
    return __builtin_bit_cast(float, u);
}
__device__ __forceinline__ short f2bf(float f) {
    unsigned int u = __builtin_bit_cast(unsigned int, f);
    u += 0x7FFFu + ((u >> 16) & 1u);
    return (short)(u >> 16);
}
__device__ __forceinline__ unsigned int pack2(float lo, float hi) {
    return (unsigned int)(unsigned short)f2bf(lo) | ((unsigned int)(unsigned short)f2bf(hi) << 16);
}
__device__ __forceinline__ float sigm(float x) {
    return __builtin_amdgcn_rcpf(1.f + exp2f(-1.4426950408889634f * x));
}
__device__ __forceinline__ float tanh_(float x) {
    return 1.f - 2.f * __builtin_amdgcn_rcpf(1.f + exp2f(2.8853900817779268f * x));
}

// ---------------------------------------------------------------------------
// xw pre-pass. Layout (ushorts):
//   xw[((((dir*64+pair)*512 + t)*8 + wv)*16 + n16)*8 + chain*4 + nt]
// Gate columns are INTERLEAVED: (wv,n16,nt) <-> gate col nt*128 + wv*16 + n16,
// i.e. nt indexes the gate type {i,f,g,o} for hidden unit wv*16+n16. This
// matches the recurrent kernel's in-register gate nonlinearity.
// ---------------------------------------------------------------------------
__global__ __launch_bounds__(512, 1)
void xw_gemm_kernel(const int* __restrict__ seq, const float* __restrict__ emb,
                    const float* __restrict__ w_ih_f, const float* __restrict__ b_ih_f,
                    const float* __restrict__ b_hh_f,
                    const float* __restrict__ w_ih_b, const float* __restrict__ b_ih_b,
                    const float* __restrict__ b_hh_b,
                    ushort_t* __restrict__ xw)
{
    __shared__ bf16x8 ldsX[64 * 17];

    const int tid  = threadIdx.x;
    const int wv   = tid >> 6;
    const int n16  = tid & 15;
    const int quad = (tid & 63) >> 4;
    const int dir  = blockIdx.x >> 10;
    const int rem  = blockIdx.x & 1023;
    const int pair = rem >> 4;
    const int tb   = (rem & 15) * 32;

    const float* wih = dir ? w_ih_b : w_ih_f;
    const float* bih = dir ? b_ih_b : b_ih_f;
    const float* bhh = dir ? b_hh_b : b_hh_f;

    // stage 64 rows: rows 0..31 chain0 (b=2*pair) t=tb..tb+31, rows 32..63 chain1
    {
        int row = tid >> 3, part = tid & 7;
        int b = 2 * pair + (row >> 5);
        int t = tb + (row & 31);
        int tok = seq[b * S_ + t];
        const float* ep = emb + (size_t)tok * EMB_ + part * 16;
        int rt = row >> 4, rr = row & 15;
#pragma unroll
        for (int h = 0; h < 2; h++) {
            float4 a = *(const float4*)(ep + h * 8);
            float4 b4 = *(const float4*)(ep + h * 8 + 4);
            bf16x8 fr;
            fr[0] = f2bf(a.x); fr[1] = f2bf(a.y); fr[2] = f2bf(a.z); fr[3] = f2bf(a.w);
            fr[4] = f2bf(b4.x); fr[5] = f2bf(b4.y); fr[6] = f2bf(b4.z); fr[7] = f2bf(b4.w);
            ldsX[(rt * 16 + part * 2 + h) * 17 + rr] = fr;
        }
    }

    bf16x8 bfrag[4][4];
    float  bias[4];
#pragma unroll
    for (int nt = 0; nt < 4; nt++) {
        int col = nt * 128 + wv * 16 + n16;   // gate-interleaved column mapping
        bias[nt] = bih[col] + bhh[col];
#pragma unroll
        for (int ks = 0; ks < 4; ks++) {
            const float* p = wih + col * EMB_ + ks * 32 + quad * 8;
            bf16x8 fr;
#pragma unroll
            for (int j = 0; j < 8; j++) fr[j] = f2bf(p[j]);
            bfrag[nt][ks] = fr;
        }
    }
    __syncthreads();

#pragma unroll
    for (int half = 0; half < 2; half++) {
        // chain0 tile = half, chain1 tile = half+2
        f32x4 accA[4], accB[4];
        bf16x8 afA[4], afB[4];
#pragma unroll
        for (int ks = 0; ks < 4; ks++) {
            afA[ks] = ldsX[(half * 16 + ks * 4 + quad) * 17 + n16];
            afB[ks] = ldsX[((half + 2) * 16 + ks * 4 + quad) * 17 + n16];
        }
#pragma unroll
        for (int nt = 0; nt < 4; nt++) {
            f32x4 a = {bias[nt], bias[nt], bias[nt], bias[nt]};
            accA[nt] = a; accB[nt] = a;
#pragma unroll
            for (int ks = 0; ks < 4; ks++) {
                accA[nt] = __builtin_amdgcn_mfma_f32_16x16x32_bf16(afA[ks], bfrag[nt][ks], accA[nt], 0, 0, 0);
                accB[nt] = __builtin_amdgcn_mfma_f32_16x16x32_bf16(afB[ks], bfrag[nt][ks], accB[nt], 0, 0, 0);
            }
        }
#pragma unroll
        for (int r = 0; r < 4; r++) {
            int t = tb + half * 16 + quad * 4 + r;
            int4 iv;
            iv.x = (int)pack2(accA[0][r], accA[1][r]);
            iv.y = (int)pack2(accA[2][r], accA[3][r]);
            iv.z = (int)pack2(accB[0][r], accB[1][r]);
            iv.w = (int)pack2(accB[2][r], accB[3][r]);
            size_t idx = ((((size_t)dir * 64 + pair) * S_ + t) * 8 + wv) * 16 + n16;
            *(int4*)(xw + idx * 8) = iv;
        }
    }
}

// ---------------------------------------------------------------------------
// Recurrent LSTM, single barrier per step:
//   - h buffer TIGHT-PACKED: ldsH[buf][(chunk*2 + chain)] bf16x8. Each af
//     ds_read_b128 touches bytes {0..127} of a 128B-aligned window -> every
//     one of the 8 distinct (quad,chain) addresses lands in a disjoint
//     4-bank group: ZERO bank conflicts (old stride-17 layout had 2-way).
//   - MFMA chains start from a hoisted zero accumulator (ZACC); the xw+bias
//     term is added at the nonlinearity from an 8B ds_read_b64 issued at
//     step top (latency hidden under the MFMA phase). Removes the per-step
//     cndmask/mov/init chain in front of the first MFMA.
//   - All lanes compute the nonlinearity (quads 2,3 are exact duplicates of
//     0,1 by the MFMA row layout); only quad<2 writes h.
// ---------------------------------------------------------------------------
#define STEP(K)                                                                    \
  {                                                                                \
    const int u = m16 + (K);                                                       \
    if ((K) == 0 && m < 31) {                                                      \
      const ushort_t* gp = xwp + (size_t)(dir ? (S_ - 32 - m16) : (m16 + 16)) * 1024; \
      sA = *(const int4*)(gp + tid * 8);                                           \
      sB = *(const int4*)(gp + 4096 + tid * 8);                                    \
      sC = *(const int4*)(gp + 8192 + tid * 8);                                    \
      sD = *(const int4*)(gp + 12288 + tid * 8);                                   \
    }                                                                              \
    /* LDS reads first: 4x af b128 (conflict-free) + 8B xv */                      \
    bf16x8 af0 = ldsH[(K) & 1][(0  + quad) * 2 + hpar];                            \
    bf16x8 af1 = ldsH[(K) & 1][(4  + quad) * 2 + hpar];                            \
    bf16x8 af2 = ldsH[(K) & 1][(8  + quad) * 2 + hpar];                            \
    bf16x8 af3 = ldsH[(K) & 1][(12 + quad) * 2 + hpar];                            \
    bf16x4 xvg = *(const bf16x4*)(xwS + ((m & 1) * 2048 + ((dir ? (15 - (K)) : (K)) * 8 + wv) * 16 + n16) * 8 + qsel); \
    if ((K) == 8 && m < 31) {                                                      \
      int4* dst = (int4*)(xwL + (((m & 1) ^ 1) * 2048));                           \
      dst[tid] = sA; dst[512 + tid] = sB; dst[1024 + tid] = sC; dst[1536 + tid] = sD; \
    }                                                                              \
    if ((K) == 1 && m >= 1 && (wv == 4 || wv == 5) && lane < 36) {                 \
      int a0 = dir ? (S_ - m16) : (m16 - 16);                                      \
      int eb = (a0 & 31) * 18 + flb;                                               \
      float4 fv;                                                                   \
      fv.x = emL[eb]; fv.y = emL[eb + 2]; fv.z = emL[eb + 4]; fv.w = emL[eb + 6];  \
      *(float4*)(emdir + (size_t)(brow0 + (wv - 4)) * (S_ * NL_) + a0 * NL_ + lane * 4) = fv; \
    }                                                                              \
    f32x4 acc0 = __builtin_amdgcn_mfma_f32_16x16x32_bf16(af0, bfrag[0][0], ZACC, 0, 0, 0); \
    f32x4 acc1 = __builtin_amdgcn_mfma_f32_16x16x32_bf16(af0, bfrag[1][0], ZACC, 0, 0, 0); \
    f32x4 acc2 = __builtin_amdgcn_mfma_f32_16x16x32_bf16(af0, bfrag[2][0], ZACC, 0, 0, 0); \
    f32x4 acc3 = __builtin_amdgcn_mfma_f32_16x16x32_bf16(af0, bfrag[3][0], ZACC, 0, 0, 0); \
    acc0 = __builtin_amdgcn_mfma_f32_16x16x32_bf16(af1, bfrag[0][1], acc0, 0, 0, 0); \
    acc1 = __builtin_amdgcn_mfma_f32_16x16x32_bf16(af1, bfrag[1][1], acc1, 0, 0, 0); \
    acc2 = __builtin_amdgcn_mfma_f32_16x16x32_bf16(af1, bfrag[2][1], acc2, 0, 0, 0); \
    acc3 = __builtin_amdgcn_mfma_f32_16x16x32_bf16(af1, bfrag[3][1], acc3, 0, 0, 0); \
    acc0 = __builtin_amdgcn_mfma_f32_16x16x32_bf16(af2, bfrag[0][2], acc0, 0, 0, 0); \
    acc1 = __builtin_amdgcn_mfma_f32_16x16x32_bf16(af2, bfrag[1][2], acc1, 0, 0, 0); \
    acc2 = __builtin_amdgcn_mfma_f32_16x16x32_bf16(af2, bfrag[2][2], acc2, 0, 0, 0); \
    acc3 = __builtin_amdgcn_mfma_f32_16x16x32_bf16(af2, bfrag[3][2], acc3, 0, 0, 0); \
    acc0 = __builtin_amdgcn_mfma_f32_16x16x32_bf16(af3, bfrag[0][3], acc0, 0, 0, 0); \
    acc1 = __builtin_amdgcn_mfma_f32_16x16x32_bf16(af3, bfrag[1][3], acc1, 0, 0, 0); \
    acc2 = __builtin_amdgcn_mfma_f32_16x16x32_bf16(af3, bfrag[2][3], acc2, 0, 0, 0); \
    acc3 = __builtin_amdgcn_mfma_f32_16x16x32_bf16(af3, bfrag[3][3], acc3, 0, 0, 0); \
    if (wv == 0) {                                                                 \
      f32x4 accE = __builtin_amdgcn_mfma_f32_16x16x32_bf16(af0, bfragE[0], ZACC, 0, 0, 0); \
      accE = __builtin_amdgcn_mfma_f32_16x16x32_bf16(af1, bfragE[1], accE, 0, 0, 0); \
      accE = __builtin_amdgcn_mfma_f32_16x16x32_bf16(af2, bfragE[2], accE, 0, 0, 0); \
      accE = __builtin_amdgcn_mfma_f32_16x16x32_bf16(af3, bfragE[3], accE, 0, 0, 0); \
      if (quad < 2 && n16 < NL_ && u >= 1) {                                       \
        int tprev = dir ? (S_ - u) : (u - 1);                                      \
        emL[((tprev & 31) * 9 + n16) * 2 + quad] = accE[0];                        \
      }                                                                            \
    }                                                                              \
    {                                                                              \
      float gi = acc0[0] + bfbits2f(xvg[0]);                                       \
      float gf = acc1[0] + bfbits2f(xvg[1]);                                       \
      float gg = acc2[0] + bfbits2f(xvg[2]);                                       \
      float go = acc3[0] + bfbits2f(xvg[3]);                                       \
      cst = sigm(gf) * cst + sigm(gi) * tanh_(gg);                                 \
      float hv = sigm(go) * tanh_(cst);                                            \
      if (quad < 2) *(((K) & 1) ? hw0 : hw1) = f2bf(hv);                           \
    }                                                                              \
    wg_bar();                                                                      \
  }

__global__ __launch_bounds__(512, 1)
void lstm_kernel(const ushort_t* __restrict__ xw,
                 const float* __restrict__ w_hh_f, const float* __restrict__ w_hh_b,
                 const float* __restrict__ w_out,
                 float* __restrict__ em_f, float* __restrict__ em_b)
{
    __shared__ bf16x8 xwL[2 * 2048];        // 64 KB: [buf][(slot*8+wv)*16+n16]
    __shared__ bf16x8 ldsH[2][32];          // 1 KB, tight: [buf][chunk*2+chain]
    __shared__ float  emL[32 * NL_ * 2];    // 2304 B: [slot][label][chain]

    const int tid  = threadIdx.x;
    const int wv   = tid >> 6;
    const int lane = tid & 63;
    const int n16  = tid & 15;
    const int quad = (tid & 63) >> 4;
    const int dir  = blockIdx.x >> 6;
    const int pair = blockIdx.x & 63;
    const int brow0 = pair * CPW_;

    const int hpar = (n16 >> 2) & 1;        // A-row chain parity
    const int qsel = (quad & 1) * 4;        // xv gate-block select (chain this lane owns)
    const int hc   = 2 * wv + (n16 >> 3);   // h chunk owned by this lane
    const int hp   = n16 & 7;               // position within chunk
    const int flb  = lane * 8 + (wv - 4);   // flush emL base (waves 4/5 only)

    // per-lane h-write pointers for the two buffers (chain = quad, quad<2 writes)
    short* hw0 = ((short*)&ldsH[0][0]) + (hc * 2 + quad) * 8 + hp;
    short* hw1 = ((short*)&ldsH[1][0]) + (hc * 2 + quad) * 8 + hp;
    const short* xwS = (const short*)xwL;

    const f32x4 ZACC = {0.f, 0.f, 0.f, 0.f};

    const float* whh = dir ? w_hh_b : w_hh_f;
    float* emdir = dir ? em_b : em_f;

    // B fragments: wave wv owns gate types nt for hidden units [wv*16, wv*16+16)
    bf16x8 bfrag[4][4];
#pragma unroll
    for (int nt = 0; nt < 4; nt++) {
        int col = nt * 128 + wv * 16 + n16;   // gate-interleaved column mapping
#pragma unroll
        for (int ks = 0; ks < 4; ks++) {
            const float* p = whh + col * H_ + ks * 32 + quad * 8;
            bf16x8 fr;
#pragma unroll
            for (int j = 0; j < 8; j++) fr[j] = f2bf(p[j]);
            bfrag[nt][ks] = fr;
        }
    }
    bf16x8 bfragE[4];
#pragma unroll
    for (int ks = 0; ks < 4; ks++) {
        bf16x8 fr = {0, 0, 0, 0, 0, 0, 0, 0};
        if (n16 < NL_) {
            const float* p = w_out + n16 * 256 + dir * 128 + ks * 32 + quad * 8;
#pragma unroll
            for (int j = 0; j < 8; j++) fr[j] = f2bf(p[j]);
        }
        bfragE[ks] = fr;
    }

    if (tid < 128) ((int*)ldsH)[tid] = 0;   // zero h buffer 0 (512 B)

    const ushort_t* xwp = xw + (size_t)(dir * 64 + pair) * ((size_t)S_ * 1024);
    // pre-stage block 0
    {
        const ushort_t* gp = xwp + (size_t)(dir ? (S_ - 16) : 0) * 1024;
        int4 a0 = *(const int4*)(gp + tid * 8);
        int4 a1 = *(const int4*)(gp + 4096 + tid * 8);
        int4 a2 = *(const int4*)(gp + 8192 + tid * 8);
        int4 a3 = *(const int4*)(gp + 12288 + tid * 8);
        int4* dst = (int4*)xwL;
        dst[tid] = a0; dst[512 + tid] = a1; dst[1024 + tid] = a2; dst[1536 + tid] = a3;
    }

    float cst = 0.f;                        // c-state: lane owns (unit, chain=quad&1)
    int4 sA, sB, sC, sD;
    wg_bar();

    for (int m = 0; m < 32; m++) {
        const int m16 = m << 4;
        STEP(0)  STEP(1)  STEP(2)  STEP(3)
        STEP(4)  STEP(5)  STEP(6)  STEP(7)
        STEP(8)  STEP(9)  STEP(10) STEP(11)
        STEP(12) STEP(13) STEP(14) STEP(15)
    }

    // final emission (h_{S}) -> emL, then tail flush. 512 steps even ->
    // final h is in buffer 0.
    if (wv == 0) {
        bf16x8 af0 = ldsH[0][(0  + quad) * 2 + hpar];
        bf16x8 af1 = ldsH[0][(4  + quad) * 2 + hpar];
        bf16x8 af2 = ldsH[0][(8  + quad) * 2 + hpar];
        bf16x8 af3 = ldsH[0][(12 + quad) * 2 + hpar];
        f32x4 accE = __builtin_amdgcn_mfma_f32_16x16x32_bf16(af0, bfragE[0], ZACC, 0, 0, 0);
        accE = __builtin_amdgcn_mfma_f32_16x16x32_bf16(af1, bfragE[1], accE, 0, 0, 0);
        accE = __builtin_amdgcn_mfma_f32_16x16x32_bf16(af2, bfragE[2], accE, 0, 0, 0);
        accE = __builtin_amdgcn_mfma_f32_16x16x32_bf16(af3, bfragE[3], accE, 0, 0, 0);
        if (quad < 2 && n16 < NL_) {
            int tprev = dir ? 0 : (S_ - 1);
            emL[((tprev & 31) * 9 + n16) * 2 + quad] = accE[0];
        }
    }
    wg_bar();
    if ((wv == 4 || wv == 5) && lane < 36) {
        int a0 = dir ? 0 : (S_ - 16);
        int eb = (a0 & 31) * 18 + flb;
        float4 fv;
        fv.x = emL[eb]; fv.y = emL[eb + 2]; fv.z = emL[eb + 4]; fv.w = emL[eb + 6];
        *(float4*)(emdir + (size_t)(brow0 + (wv - 4)) * (S_ * NL_) + a0 * NL_ + lane * 4) = fv;
    }
}

// ---------------------------------------------------------------------------
// CRF with chunked parallel scan (unchanged — verified correct).
// ---------------------------------------------------------------------------
__global__ __launch_bounds__(640, 1)
void crf_kernel(const int* __restrict__ seq, const int* __restrict__ lab,
                const float* __restrict__ em_f, const float* __restrict__ em_b,
                const float* __restrict__ b_out,
                const float* __restrict__ start_t, const float* __restrict__ end_t,
                const float* __restrict__ trans, float* __restrict__ partial)
{
    __shared__ float emS[S_ * NL_];
    __shared__ float transS[NL_ * NL_];
    __shared__ float stS[NL_], enS[NL_];
    __shared__ unsigned char maskS[S_];
    __shared__ float MS[7 * 81];
    __shared__ float vS[NL_];
    __shared__ float redw[10];
    __shared__ int   redl[10];

    const int b = blockIdx.x, tid = threadIdx.x;
    const size_t base = (size_t)b * S_ * NL_;
    const float L2E = 1.4426950408889634f, LN2 = 0.6931471805599453f;

    for (int q = tid; q < S_ * NL_; q += 640)
        emS[q] = em_f[base + q] + em_b[base + q] + b_out[q % NL_];
    if (tid < NL_ * NL_) transS[tid] = trans[tid];
    if (tid < NL_) { stS[tid] = start_t[tid]; enS[tid] = end_t[tid]; }
    if (tid < S_) maskS[tid] = (seq[b * S_ + tid] != 0);
    __syncthreads();

    float np = 0.f; int myc = 0;
    if (tid < S_) {
        myc = maskS[tid];
        if (tid >= 1 && maskS[tid]) {
            int lp = lab[b * S_ + tid - 1], lc = lab[b * S_ + tid];
            np = transS[lp * NL_ + lc] + emS[tid * NL_ + lc];
        }
    }
#pragma unroll
    for (int off = 32; off; off >>= 1) {
        np  += __shfl_down(np, off, 64);
        myc += __shfl_down(myc, off, 64);
    }
    if ((tid & 63) == 0) { redw[tid >> 6] = np; redl[tid >> 6] = myc; }

    const int w = tid >> 6, l = tid & 63;
    const int lg = l / 9;
    const int g  = w * 7 + lg;
    const bool sact = (lg < 7) && (g < 64);
    const int jj = sact ? (l - lg * 9) : 0;
    const int gb = sact ? lg * 9 : 0;
    float Tc[NL_];
#pragma unroll
    for (int i = 0; i < NL_; i++) Tc[i] = transS[i * NL_ + jj];
    float sc; int tbeg, tend, cN = 0, iN = 0;
    if (sact && g == 0) {
        sc = stS[jj] + emS[jj];
        tbeg = 1; tend = 64;
    } else if (sact) {
        cN = 1 + (g - 1) / 9; iN = (g - 1) % 9;
        sc = (jj == iN) ? 0.f : -1e30f;
        tbeg = cN * 64; tend = tbeg + 64;
    } else {
        sc = -1e30f; tbeg = 448; tend = 512;
    }
    for (int t = tbeg; t < tend; t++) {
        float emv = emS[t * NL_ + jj];
        float a[NL_];
#pragma unroll
        for (int i = 0; i < NL_; i++) a[i] = __shfl(sc, gb + i, 64) + Tc[i];
        float m = a[0];
#pragma unroll
        for (int i = 1; i < NL_; i++) m = fmaxf(m, a[i]);
        float sum = 0.f;
#pragma unroll
        for (int i = 0; i < NL_; i++) sum += exp2f((a[i] - m) * L2E);
        float nxt = emv + m + LN2 * log2f(sum);
        sc = maskS[t] ? nxt : sc;
    }
    if (sact) {
        if (g == 0) vS[jj] = sc;
        else MS[(cN - 1) * 81 + iN * NL_ + jj] = sc;
    }
    __syncthreads();

    if (tid < 64) {
        const int j = (tid < NL_) ? tid : (NL_ - 1);
        float v = vS[j];
        for (int c = 1; c < 8; c++) {
            float a[NL_];
#pragma unroll
            for (int i = 0; i < NL_; i++)
                a[i] = __shfl(v, i, 64) + MS[(c - 1) * 81 + i * NL_ + j];
            float m = a[0];
#pragma unroll
            for (int i = 1; i < NL_; i++) m = fmaxf(m, a[i]);
            float sum = 0.f;
#pragma unroll
            for (int i = 0; i < NL_; i++) sum += exp2f((a[i] - m) * L2E);
            v = m + LN2 * log2f(sum);
        }
        v += enS[j];
        float mm = -1e30f, av[NL_];
#pragma unroll
        for (int i = 0; i < NL_; i++) { float vi = __shfl(v, i, 64); av[i] = vi; mm = fmaxf(mm, vi); }
        float ss = 0.f;
#pragma unroll
        for (int i = 0; i < NL_; i++) ss += exp2f((av[i] - mm) * L2E);
        if (tid == 0) {
            float num = 0.f; int len = 0;
#pragma unroll
            for (int ww = 0; ww < 10; ww++) { num += redw[ww]; len += redl[ww]; }
            int l0 = lab[b * S_];
            int ll = lab[b * S_ + len - 1];
            num += stS[l0] + emS[l0] + enS[ll];
            partial[b] = (mm + LN2 * log2f(ss)) - num;
        }
    }
}

__global__ __launch_bounds__(128)
void reduce_kernel(const float* __restrict__ partial, float* __restrict__ out)
{
    __shared__ float s[128];
    int tid = threadIdx.x;
    s[tid] = partial[tid];
    __syncthreads();
    for (int off = 64; off; off >>= 1) {
        if (tid < off) s[tid] += s[tid + off];
        __syncthreads();
    }
    if (tid == 0) out[0] = s[0];
}

extern "C" void kernel_launch(void* const* d_in, const int* in_sizes, int n_in,
                              void* d_out, int out_size, void* d_ws, size_t ws_size,
                              hipStream_t stream)
{
    const int* seq = (const int*)d_in[0];
    const int* lab = (const int*)d_in[1];
    const float* emb    = (const float*)d_in[2];
    const float* w_ih_f = (const float*)d_in[3];
    const float* w_hh_f = (const float*)d_in[4];
    const float* b_ih_f = (const float*)d_in[5];
    const float* b_hh_f = (const float*)d_in[6];
    const float* w_ih_b = (const float*)d_in[7];
    const float* w_hh_b = (const float*)d_in[8];
    const float* b_ih_b = (const float*)d_in[9];
    const float* b_hh_b = (const float*)d_in[10];
    const float* w_out  = (const float*)d_in[11];
    const float* b_out  = (const float*)d_in[12];
    const float* start_t = (const float*)d_in[13];
    const float* end_t   = (const float*)d_in[14];
    const float* trans   = (const float*)d_in[15];

    char* ws = (char*)d_ws;
    const size_t xw_bytes = (size_t)2 * B_ * S_ * G_ * sizeof(ushort_t);  // 134.2 MB
    const size_t em_bytes = (size_t)B_ * S_ * NL_ * sizeof(float);
    ushort_t* xw   = (ushort_t*)ws;
    float* em_f    = (float*)(ws + xw_bytes);
    float* em_b    = (float*)(ws + xw_bytes + em_bytes);
    float* partial = (float*)(ws + xw_bytes + 2 * em_bytes);

    xw_gemm_kernel<<<dim3(2048), dim3(512), 0, stream>>>(seq, emb,
        w_ih_f, b_ih_f, b_hh_f, w_ih_b, b_ih_b, b_hh_b, xw);
    lstm_kernel<<<dim3(128), dim3(512), 0, stream>>>(xw, w_hh_f, w_hh_b,
        w_out, em_f, em_b);
    crf_kernel<<<dim3(B_), dim3(640), 0, stream>>>(seq, lab, em_f, em_b, b_out,
        start_t, end_t, trans, partial);
    reduce_kernel<<<dim3(1), dim3(128), 0, stream>>>(partial, (float*)d_out);
}